// Round 1
// baseline (223.892 us; speedup 1.0000x reference)
//
#include <hip/hip_runtime.h>

// FNNKernelTransform: out[e,i] = sum_j mat[e,i,j]*v[e,j] + bias[e,i]
// where [mat|bias] = reshape(MLP([pos_i,pos_j]), [32,33]).
// Restructured: out[e,i] = sum_{k=0..128} h2ext[e,k] * ( vext[e,0:32] . Bk[:,i] + Wb[k,i] )
//   Bk[j,i] = W3[k, i*33+j] (k<128), = b3[i*33+j] (k==128);  Wb[k,i] = W3[k,i*33+32] / b3[...]
// Dominant GEMM becomes K=32 MFMA with per-wave-resident A (vext), Wb folded into MFMA C-operand.
// ws usage: Wg (bf16 fragment-packed, 132*1024 elems = 270336 B) @ 0
//           W2f (bf16 fragment-packed, 16384 elems = 32768 B)     @ 270336
//           Wbp (f32, 132*32 = 4224 elems = 16896 B)              @ 303104
//           total 320000 B

#define E_TOTAL 262144
#define EPB 128
#define NBLK (E_TOTAL / EPB)

typedef float f32x4 __attribute__((ext_vector_type(4)));
typedef short s8v  __attribute__((ext_vector_type(8)));

__device__ __forceinline__ unsigned short f2bf(float x) {
  unsigned u = __float_as_uint(x);
  u += 0x7fffu + ((u >> 16) & 1u);   // round-to-nearest-even
  return (unsigned short)(u >> 16);
}
__device__ __forceinline__ float bf2f(unsigned short h) {
  return __uint_as_float(((unsigned)h) << 16);
}

// ---------------- prep: pack W3/b3/W2 into MFMA-fragment order ----------------
__global__ void prep_pack(const float* __restrict__ W2, const float* __restrict__ W3,
                          const float* __restrict__ b3,
                          unsigned short* __restrict__ Wg, unsigned short* __restrict__ W2f,
                          float* __restrict__ Wbp) {
  int idx = blockIdx.x * 256 + threadIdx.x;   // grid covers 135168 = 132*1024
  // Wg[(kk*2+ih)*512 + lane*8 + jj] = B-frag elem: n=i=ih*16+(lane&15), k=j=(lane>>4)*8+jj
  if (idx < 132 * 1024) {
    int kk = idx >> 10;
    int rem = idx & 1023;
    int ih = rem >> 9;
    int l = (rem >> 3) & 63;
    int jj = idx & 7;
    int i = ih * 16 + (l & 15);
    int j = ((l >> 4) << 3) + jj;
    int col = i * 33 + j;
    float v = (kk < 128) ? W3[kk * 1056 + col] : (kk == 128 ? b3[col] : 0.f);
    Wg[idx] = f2bf(v);
  }
  // W2f[((ks*8+nt)*64 + lane)*8 + jj]: n=nt*16+(lane&15), k=ks*32+(lane>>4)*8+jj
  if (idx < 16384) {
    int ks = idx >> 12;
    int nt = (idx >> 9) & 7;
    int l = (idx >> 3) & 63;
    int jj = idx & 7;
    int k = ks * 32 + ((l >> 4) << 3) + jj;
    int n = nt * 16 + (l & 15);
    W2f[idx] = f2bf(W2[k * 128 + n]);
  }
  // Wbp[kk*32 + i]
  if (idx < 132 * 32) {
    int kk = idx >> 5;
    int i = idx & 31;
    Wbp[idx] = (kk < 128) ? W3[kk * 1056 + i * 33 + 32]
                          : (kk == 128 ? b3[i * 33 + 32] : 0.f);
  }
}

// ---------------- fused main kernel ----------------
// 256 threads (4 waves), 128 edges/block. LDS: h2T 34848 + Bbuf 16384 + h1c 8704 = 59936 B
// -> 2 blocks/CU -> 2 waves/SIMD (MFMA/VALU overlap).
__global__ __launch_bounds__(256, 2) void fnn_fused(
    const float* __restrict__ pos_i, const float* __restrict__ pos_j,
    const float* __restrict__ vj, const float* __restrict__ W1,
    const float* __restrict__ b1, const float* __restrict__ b2,
    const unsigned short* __restrict__ W2f, const unsigned short* __restrict__ Wg,
    const float* __restrict__ Wbp, float* __restrict__ out) {
  // h2T[k][e]: rows 0..127 = h2 (bf16), row 128 = 1.0, rows 129..131 = 0. stride 132 (bank pad)
  __shared__ __attribute__((aligned(16))) unsigned short h2T[132 * 132];
  __shared__ __attribute__((aligned(16))) unsigned short Bbuf[2][4096];
  __shared__ __attribute__((aligned(16))) unsigned short h1c[32 * 136]; // stride 136 (bank pad)

  const int tid = threadIdx.x;
  const int w = tid >> 6, lane = tid & 63, q = lane >> 4, ln = lane & 15;
  const int B0 = blockIdx.x * EPB;

  // --- G-GEMM A-fragments (vext bf16, A[m=lane&15][k=quad*8+j]) -- persistent ---
  s8v av[2];
#pragma unroll
  for (int m = 0; m < 2; ++m) {
    int e = B0 + w * 32 + m * 16 + ln;
    const float4 va = *(const float4*)(vj + (size_t)e * 32 + q * 8);
    const float4 vb = *(const float4*)(vj + (size_t)e * 32 + q * 8 + 4);
    s8v t;
    t[0] = (short)f2bf(va.x); t[1] = (short)f2bf(va.y);
    t[2] = (short)f2bf(va.z); t[3] = (short)f2bf(va.w);
    t[4] = (short)f2bf(vb.x); t[5] = (short)f2bf(vb.y);
    t[6] = (short)f2bf(vb.z); t[7] = (short)f2bf(vb.w);
    av[m] = t;
  }

  // --- W1/b1 per-thread register slice (thread owns 8 hidden cols) ---
  const int hh0 = (tid & 15) * 8;
  float w1r[4][8], b1r[8];
#pragma unroll
  for (int d = 0; d < 4; ++d)
#pragma unroll
    for (int u = 0; u < 8; ++u) w1r[d][u] = W1[d * 128 + hh0 + u];
#pragma unroll
  for (int u = 0; u < 8; ++u) b1r[u] = b1[hh0 + u];

  // --- stage 1 + 2: build h2T for this block's 128 edges, in 4 chunks of 32 edges ---
  for (int cb = 0; cb < 4; ++cb) {
#pragma unroll
    for (int half = 0; half < 2; ++half) {
      int ee = (tid >> 4) + half * 16;     // 0..31
      int eg = B0 + cb * 32 + ee;
      const float2 pi = *(const float2*)(pos_i + (size_t)eg * 2);
      const float2 pj = *(const float2*)(pos_j + (size_t)eg * 2);
      s8v hv;
#pragma unroll
      for (int u = 0; u < 8; ++u) {
        float o = b1r[u] + pi.x * w1r[0][u] + pi.y * w1r[1][u] +
                  pj.x * w1r[2][u] + pj.y * w1r[3][u];
        o = fmaxf(o, 0.f);
        hv[u] = (short)f2bf(o);
      }
      *(s8v*)&h1c[ee * 136 + hh0] = hv;
    }
    __syncthreads();
    // stage 2: h2 = relu(h1 @ W2 + b2); 16 tiles (2 Mt x 8 Nt), 4 per wave
#pragma unroll
    for (int s = 0; s < 4; ++s) {
      int tt = w * 4 + s, mt = tt >> 3, nt = tt & 7;
      f32x4 a4 = {0.f, 0.f, 0.f, 0.f};
#pragma unroll
      for (int ks = 0; ks < 4; ++ks) {
        s8v af = *(const s8v*)&h1c[(mt * 16 + ln) * 136 + ks * 32 + q * 8];
        s8v bf = *(const s8v*)(W2f + ((ks * 8 + nt) * 64 + lane) * 8);
        a4 = __builtin_amdgcn_mfma_f32_16x16x32_bf16(af, bf, a4, 0, 0, 0);
      }
      float b2v = b2[nt * 16 + ln];
      // D layout: row(e) = q*4+r, col(k') = ln; write transposed into h2T[k'][e]
      unsigned h01 = (unsigned)f2bf(fmaxf(a4[0] + b2v, 0.f)) |
                     ((unsigned)f2bf(fmaxf(a4[1] + b2v, 0.f)) << 16);
      unsigned h23 = (unsigned)f2bf(fmaxf(a4[2] + b2v, 0.f)) |
                     ((unsigned)f2bf(fmaxf(a4[3] + b2v, 0.f)) << 16);
      uint2 pw; pw.x = h01; pw.y = h23;
      *(uint2*)&h2T[(nt * 16 + ln) * 132 + cb * 32 + mt * 16 + q * 4] = pw;
    }
    __syncthreads();
  }
  // h2ext pad rows: k=128 -> 1.0 (carries b3 terms), 129..131 -> 0 (chunk pad)
  if (tid < 128) {
    h2T[128 * 132 + tid] = 0x3F80;
    h2T[129 * 132 + tid] = 0;
    h2T[130 * 132 + tid] = 0;
    h2T[131 * 132 + tid] = 0;
  }
  // stage B chunk 0 (kk 0..3): 8 KB
  {
    s8v t0 = *(const s8v*)(Wg + tid * 8);
    s8v t1 = *(const s8v*)(Wg + 2048 + tid * 8);
    *(s8v*)&Bbuf[0][tid * 8] = t0;
    *(s8v*)&Bbuf[0][2048 + tid * 8] = t1;
  }
  __syncthreads();

  float acc[2][2][4];
#pragma unroll
  for (int m = 0; m < 2; ++m)
#pragma unroll
    for (int ih = 0; ih < 2; ++ih)
#pragma unroll
      for (int r = 0; r < 4; ++r) acc[m][ih][r] = 0.f;

  // --- G-loop: 33 chunks x 4 kk. Per kk: Gtile = vext·Bk + Wb(C-init); acc += h2[e,kk]*Gtile
  for (int c = 0; c < 33; ++c) {
    const int bb = c & 1;
    s8v n0, n1;
    const bool have = (c < 32);
    if (have) {
      n0 = *(const s8v*)(Wg + (c + 1) * 4096 + tid * 8);
      n1 = *(const s8v*)(Wg + (c + 1) * 4096 + 2048 + tid * 8);
    }
#pragma unroll
    for (int kd = 0; kd < 4; ++kd) {
      const int kk = c * 4 + kd;
      float hf[2][4];
#pragma unroll
      for (int m = 0; m < 2; ++m) {
        uint2 hv = *(const uint2*)&h2T[kk * 132 + w * 32 + m * 16 + q * 4];
        hf[m][0] = bf2f((unsigned short)(hv.x & 0xffffu));
        hf[m][1] = bf2f((unsigned short)(hv.x >> 16));
        hf[m][2] = bf2f((unsigned short)(hv.y & 0xffffu));
        hf[m][3] = bf2f((unsigned short)(hv.y >> 16));
      }
#pragma unroll
      for (int ih = 0; ih < 2; ++ih) {
        float wb = Wbp[kk * 32 + ih * 16 + ln];
        f32x4 ci = {wb, wb, wb, wb};
        s8v bf = *(const s8v*)&Bbuf[bb][(kd * 2 + ih) * 512 + lane * 8];
#pragma unroll
        for (int m = 0; m < 2; ++m) {
          f32x4 g = __builtin_amdgcn_mfma_f32_16x16x32_bf16(av[m], bf, ci, 0, 0, 0);
          acc[m][ih][0] += hf[m][0] * g[0];
          acc[m][ih][1] += hf[m][1] * g[1];
          acc[m][ih][2] += hf[m][2] * g[2];
          acc[m][ih][3] += hf[m][3] * g[3];
        }
      }
    }
    if (have) {
      *(s8v*)&Bbuf[bb ^ 1][tid * 8] = n0;
      *(s8v*)&Bbuf[bb ^ 1][2048 + tid * 8] = n1;
    }
    __syncthreads();
  }

  // --- epilogue: out[e, i] f32 ---
#pragma unroll
  for (int m = 0; m < 2; ++m)
#pragma unroll
    for (int ih = 0; ih < 2; ++ih)
#pragma unroll
      for (int r = 0; r < 4; ++r) {
        int e = B0 + w * 32 + m * 16 + q * 4 + r;
        out[(size_t)e * 32 + ih * 16 + ln] = acc[m][ih][r];
      }
}

extern "C" void kernel_launch(void* const* d_in, const int* in_sizes, int n_in,
                              void* d_out, int out_size, void* d_ws, size_t ws_size,
                              hipStream_t stream) {
  const float* pos_i = (const float*)d_in[0];
  const float* pos_j = (const float*)d_in[1];
  const float* vj    = (const float*)d_in[2];
  const float* W1    = (const float*)d_in[3];
  const float* b1    = (const float*)d_in[4];
  const float* W2    = (const float*)d_in[5];
  const float* b2    = (const float*)d_in[6];
  const float* W3    = (const float*)d_in[7];
  const float* b3    = (const float*)d_in[8];
  float* outp = (float*)d_out;

  unsigned short* Wg  = (unsigned short*)d_ws;
  unsigned short* W2f = (unsigned short*)((char*)d_ws + 270336);
  float*          Wbp = (float*)((char*)d_ws + 303104);

  prep_pack<<<528, 256, 0, stream>>>(W2, W3, b3, Wg, W2f, Wbp);
  fnn_fused<<<NBLK, 256, 0, stream>>>(pos_i, pos_j, vj, W1, b1, b2, W2f, Wg, Wbp, outp);
}

// Round 2
// 185.552 us; speedup vs baseline: 1.2066x; 1.2066x over previous
//
#include <hip/hip_runtime.h>

// out[e,i] = sum_j mat[e,i,j] v[e,j] + bias[e,i],  [mat|bias] = MLP(pos).reshape(32,33)
// Round-2 structure: per block of 256 edges,
//   P[e, col] = h2[e,0:128] @ Wpack[0:128, col]   (col = j*32+i, j in 0..32; W3-only)
//   out[e,i]  = sum_{col: i} vext[e,j] * P[e,col] + (small GEMM: sum_j v[e,j] b3[i*33+j] + b3[i*33+32])
// A (h2) fragments resident in VGPRs; P per n-tile from zero-quad C; einsum fused as epilogue FMA.
// ws: Wg2 @0 (270336 B), W2f @270336 (32768 B), b3f @303104 (2048 B), b3c @305152 (128 B)

#define E_TOTAL 262144
#define EPB 256
#define NBLK (E_TOTAL / EPB)

typedef float f32x4 __attribute__((ext_vector_type(4)));
typedef short s8v  __attribute__((ext_vector_type(8)));

__device__ __forceinline__ unsigned short f2bf(float x) {
  unsigned u = __float_as_uint(x);
  u += 0x7fffu + ((u >> 16) & 1u);
  return (unsigned short)(u >> 16);
}

// ---------------- prep: pack W2/W3/b3 into MFMA B-fragment order ----------------
__global__ void prep_pack(const float* __restrict__ W2, const float* __restrict__ W3,
                          const float* __restrict__ b3,
                          unsigned short* __restrict__ Wg2, unsigned short* __restrict__ W2f,
                          unsigned short* __restrict__ b3f, float* __restrict__ b3c) {
  int idx = blockIdx.x * 256 + threadIdx.x;   // 528 blocks cover 135168
  if (idx < 135168) {
    // Wg2[((nn*4+ks)*64 + lane)*8 + jj] : B[k=ks*32+(lane>>4)*8+jj][col]
    // nn is the PERMUTED tile order: nn<33 -> tile 2*nn (ih=0), else tile 2*(nn-33)+1 (ih=1)
    int jj = idx & 7, lane = (idx >> 3) & 63;
    int ksnn = idx >> 9, ks = ksnn & 3, nn = ksnn >> 2;
    int nnt = (nn < 33) ? (2 * nn) : (2 * (nn - 33) + 1);
    int k = ks * 32 + ((lane >> 4) << 3) + jj;
    int col = nnt * 16 + (lane & 15);        // col = j*32 + i
    int i = col & 31, j = col >> 5;
    Wg2[idx] = f2bf(W3[k * 1056 + i * 33 + j]);
  }
  if (idx < 16384) {
    // W2f[((ks*8+nt)*64 + lane)*8 + jj]: n=nt*16+(lane&15), k=ks*32+(lane>>4)*8+jj
    int ks = idx >> 12, nt = (idx >> 9) & 7, l = (idx >> 3) & 63, jj = idx & 7;
    int k = ks * 32 + ((l >> 4) << 3) + jj;
    int n = nt * 16 + (l & 15);
    W2f[idx] = f2bf(W2[k * 128 + n]);
  }
  if (idx < 1024) {
    // b3f[(ih*64+lane)*8+jj]: B[k=j][n=i] = b3[i*33+j], j<32
    int jj = idx & 7, lane = (idx >> 3) & 63, ih = idx >> 9;
    int j = ((lane >> 4) << 3) + jj, i = ih * 16 + (lane & 15);
    b3f[idx] = f2bf(b3[i * 33 + j]);
  }
  if (idx < 32) b3c[idx] = b3[idx * 33 + 32];
}

// ---------------- G-loop chunk body (IH compile-time: out-acc half) ----------------
template <int IH>
__device__ __forceinline__ void g_chunk(const unsigned short* __restrict__ buf,
                                        const float* __restrict__ vt,
                                        int j0, int lane, int eoff,
                                        const s8v (&af)[4][4], float (&oa)[2][4][4]) {
  const f32x4 zero4 = {0.f, 0.f, 0.f, 0.f};
#pragma unroll
  for (int t = 0; t < 3; ++t) {
    const int j = j0 + t;
    s8v bfr[4];
#pragma unroll
    for (int ks = 0; ks < 4; ++ks)
      bfr[ks] = *(const s8v*)&buf[(t * 4 + ks) * 512 + lane * 8];
    f32x4 p[4];
#pragma unroll
    for (int m = 0; m < 4; ++m) {
      p[m] = __builtin_amdgcn_mfma_f32_16x16x32_bf16(af[m][0], bfr[0], zero4, 0, 0, 0);
#pragma unroll
      for (int ks = 1; ks < 4; ++ks)
        p[m] = __builtin_amdgcn_mfma_f32_16x16x32_bf16(af[m][ks], bfr[ks], p[m], 0, 0, 0);
    }
    const float* vp = vt + j * 260 + eoff;
#pragma unroll
    for (int m = 0; m < 4; ++m) {
      f32x4 vv = *(const f32x4*)(vp + m * 16);
#pragma unroll
      for (int r = 0; r < 4; ++r) oa[IH][m][r] += vv[r] * p[m][r];
    }
  }
}

// ---------------- fused main kernel ----------------
// 256 threads (4 waves), 256 edges/block; wave w owns edges [B0+w*64, B0+w*64+64).
// LDS: vt f32[33][260] @0 (34320) | transient: h2n u16[64][136] @34320 (17408),
//      h1c u16[32][136] @51728 (8704) | Bbuf u16[2][6144] @34320 (24576, reuses h2n/h1c)
// total 60432 B -> 2 blocks/CU -> 2 waves/SIMD.
__global__ __launch_bounds__(256, 2) void fnn_fused(
    const float* __restrict__ pos_i, const float* __restrict__ pos_j,
    const float* __restrict__ vj, const float* __restrict__ W1,
    const float* __restrict__ b1, const float* __restrict__ b2,
    const unsigned short* __restrict__ W2f, const unsigned short* __restrict__ Wg2,
    const unsigned short* __restrict__ b3f, const float* __restrict__ b3c,
    float* __restrict__ out) {
  __shared__ __attribute__((aligned(16))) char smem[60432];
  float* vt = (float*)smem;                                  // [33][260]
  unsigned short* h2n = (unsigned short*)(smem + 34320);     // [64][136]
  unsigned short* h1c = (unsigned short*)(smem + 51728);     // [32][136]
  unsigned short* Bb  = (unsigned short*)(smem + 34320);     // [2][6144]

  const int tid = threadIdx.x;
  const int w = tid >> 6, lane = tid & 63, q = lane >> 4, ln = lane & 15;
  const int B0 = blockIdx.x * EPB;
  const int eoff = w * 64 + q * 4;

  // --- build vt: vt[j][e] = v[e,j] (f32), row 32 = 1.0 ---
  {
    const float* vrow = vj + (size_t)(B0 + tid) * 32;
#pragma unroll
    for (int j4 = 0; j4 < 8; ++j4) {
      float4 vv = *(const float4*)(vrow + j4 * 4);
      vt[(j4 * 4 + 0) * 260 + tid] = vv.x;
      vt[(j4 * 4 + 1) * 260 + tid] = vv.y;
      vt[(j4 * 4 + 2) * 260 + tid] = vv.z;
      vt[(j4 * 4 + 3) * 260 + tid] = vv.w;
    }
    vt[32 * 260 + tid] = 1.0f;
  }

  // --- out-acc init via b3 mini-GEMM: oa[ih][m][r] = sum_j v[e,j] b3[i*33+j] + b3[i*33+32] ---
  float oa[2][4][4];
  {
    s8v av[4];
#pragma unroll
    for (int m = 0; m < 4; ++m) {
      int e = B0 + w * 64 + m * 16 + ln;
      const float4 va = *(const float4*)(vj + (size_t)e * 32 + q * 8);
      const float4 vb = *(const float4*)(vj + (size_t)e * 32 + q * 8 + 4);
      s8v t;
      t[0] = (short)f2bf(va.x); t[1] = (short)f2bf(va.y);
      t[2] = (short)f2bf(va.z); t[3] = (short)f2bf(va.w);
      t[4] = (short)f2bf(vb.x); t[5] = (short)f2bf(vb.y);
      t[6] = (short)f2bf(vb.z); t[7] = (short)f2bf(vb.w);
      av[m] = t;
    }
#pragma unroll
    for (int ih = 0; ih < 2; ++ih) {
      s8v b3fr = *(const s8v*)(b3f + (ih * 64 + lane) * 8);
      float cbv = b3c[ih * 16 + ln];
      f32x4 ci = {cbv, cbv, cbv, cbv};
#pragma unroll
      for (int m = 0; m < 4; ++m) {
        f32x4 p = __builtin_amdgcn_mfma_f32_16x16x32_bf16(av[m], b3fr, ci, 0, 0, 0);
#pragma unroll
        for (int r = 0; r < 4; ++r) oa[ih][m][r] = p[r];
      }
    }
  }

  // --- W1/b1 register slice: thread owns 8 hidden cols for stage 1 ---
  const int hh0 = (tid & 15) * 8;
  float w1r[4][8], b1r[8];
#pragma unroll
  for (int d = 0; d < 4; ++d)
#pragma unroll
    for (int u = 0; u < 8; ++u) w1r[d][u] = W1[d * 128 + hh0 + u];
#pragma unroll
  for (int u = 0; u < 8; ++u) b1r[u] = b1[hh0 + u];

  // --- stages 1+2 per quarter (64 edges), extract A-frags to registers ---
  s8v af[4][4];
  for (int qtr = 0; qtr < 4; ++qtr) {
    for (int cb = 0; cb < 2; ++cb) {
#pragma unroll
      for (int half = 0; half < 2; ++half) {
        int ee = (tid >> 4) + half * 16;
        int eg = B0 + qtr * 64 + cb * 32 + ee;
        float2 pi = *(const float2*)(pos_i + (size_t)eg * 2);
        float2 pj = *(const float2*)(pos_j + (size_t)eg * 2);
        s8v hv;
#pragma unroll
        for (int u = 0; u < 8; ++u) {
          float o = b1r[u] + pi.x * w1r[0][u] + pi.y * w1r[1][u] +
                    pj.x * w1r[2][u] + pj.y * w1r[3][u];
          hv[u] = (short)f2bf(fmaxf(o, 0.f));
        }
        *(s8v*)&h1c[ee * 136 + hh0] = hv;
      }
      __syncthreads();
#pragma unroll
      for (int s = 0; s < 4; ++s) {
        int tt = w * 4 + s, mt = tt >> 3, nt = tt & 7;
        f32x4 a4 = {0.f, 0.f, 0.f, 0.f};
#pragma unroll
        for (int ks = 0; ks < 4; ++ks) {
          s8v afr = *(const s8v*)&h1c[(mt * 16 + ln) * 136 + ks * 32 + q * 8];
          s8v bfr = *(const s8v*)(W2f + ((ks * 8 + nt) * 64 + lane) * 8);
          a4 = __builtin_amdgcn_mfma_f32_16x16x32_bf16(afr, bfr, a4, 0, 0, 0);
        }
        float b2v = b2[nt * 16 + ln];
        int eb = cb * 32 + mt * 16 + q * 4;
        int kc = nt * 16 + ln;
#pragma unroll
        for (int r = 0; r < 4; ++r)
          h2n[(eb + r) * 136 + kc] = f2bf(fmaxf(a4[r] + b2v, 0.f));
      }
      __syncthreads();
    }
    if (w == qtr) {
#pragma unroll
      for (int m = 0; m < 4; ++m)
#pragma unroll
        for (int ks = 0; ks < 4; ++ks)
          af[m][ks] = *(const s8v*)&h2n[(m * 16 + ln) * 136 + ks * 32 + q * 8];
    }
    __syncthreads();   // extraction reads drained before h2n reuse
  }

  // --- G-loop: 22 chunks x 3 n-tiles, double-buffered B staging (register roundtrip) ---
  s8v pre[3];
#pragma unroll
  for (int t = 0; t < 3; ++t) pre[t] = *(const s8v*)(Wg2 + (t * 256 + tid) * 8);
#pragma unroll
  for (int t = 0; t < 3; ++t) *(s8v*)&Bb[(t * 256 + tid) * 8] = pre[t];
  __syncthreads();

  for (int c = 0; c < 22; ++c) {
    const int bb = c & 1;
    const unsigned short* buf = Bb + bb * 6144;
    if (c + 1 < 22) {
#pragma unroll
      for (int t = 0; t < 3; ++t)
        pre[t] = *(const s8v*)(Wg2 + (c + 1) * 6144 + (t * 256 + tid) * 8);
    }
    if (c < 11) g_chunk<0>(buf, vt, c * 3, lane, eoff, af, oa);
    else        g_chunk<1>(buf, vt, (c - 11) * 3, lane, eoff, af, oa);
    if (c + 1 < 22) {
      unsigned short* nb = Bb + (bb ^ 1) * 6144;
#pragma unroll
      for (int t = 0; t < 3; ++t) *(s8v*)&nb[(t * 256 + tid) * 8] = pre[t];
    }
    __syncthreads();
  }

  // --- epilogue: out[e,i] f32 ---
#pragma unroll
  for (int m = 0; m < 4; ++m)
#pragma unroll
    for (int ih = 0; ih < 2; ++ih)
#pragma unroll
      for (int r = 0; r < 4; ++r) {
        int e = B0 + w * 64 + m * 16 + q * 4 + r;
        out[(size_t)e * 32 + ih * 16 + ln] = oa[ih][m][r];
      }
}

extern "C" void kernel_launch(void* const* d_in, const int* in_sizes, int n_in,
                              void* d_out, int out_size, void* d_ws, size_t ws_size,
                              hipStream_t stream) {
  const float* pos_i = (const float*)d_in[0];
  const float* pos_j = (const float*)d_in[1];
  const float* vj    = (const float*)d_in[2];
  const float* W1    = (const float*)d_in[3];
  const float* b1    = (const float*)d_in[4];
  const float* W2    = (const float*)d_in[5];
  const float* b2    = (const float*)d_in[6];
  const float* W3    = (const float*)d_in[7];
  const float* b3    = (const float*)d_in[8];
  float* outp = (float*)d_out;

  unsigned short* Wg2 = (unsigned short*)d_ws;
  unsigned short* W2f = (unsigned short*)((char*)d_ws + 270336);
  unsigned short* b3f = (unsigned short*)((char*)d_ws + 303104);
  float*          b3c = (float*)((char*)d_ws + 305152);

  prep_pack<<<528, 256, 0, stream>>>(W2, W3, b3, Wg2, W2f, b3f, b3c);
  fnn_fused<<<NBLK, 256, 0, stream>>>(pos_i, pos_j, vj, W1, b1, b2, W2f, Wg2, b3f, b3c, outp);
}